// Round 16
// baseline (52.552 us; speedup 1.0000x reference)
//
#include <hip/hip_runtime.h>

#define B_ 8
#define N_ 256
#define D_ 512

// async 16B global -> LDS. FULL-WAVE ONLY (exec-masked LDS-DMA corrupts LDS).
__device__ __forceinline__ void load_lds_16B(const float* g, float* l)
{
    __builtin_amdgcn_global_load_lds(
        (const __attribute__((address_space(1))) void*)g,
        (__attribute__((address_space(3))) void*)l, 16, 0, 0);
}

// counted-vmcnt pipeline sync: wait own oldest DMA loads down to <=n
// outstanding, then barrier. Both asm with "memory" clobber: the barrier
// must be a compiler fence (raw __builtin s_barrier is IntrNoMem and LLVM
// may hoist LDS reads across it). vmcnt waits oldest-first [m135].
#define PIPE_SYNC(n)                                                   \
    do {                                                               \
        asm volatile("s_waitcnt vmcnt(" #n ")" ::: "memory");          \
        asm volatile("s_barrier" ::: "memory");                        \
    } while (0)

// ================= Kernel A: scores S[b][i][j] = -sum_d |q-k| =============
// grid 1024: b=bid&7, itile=(bid>>3)&31 -> 8 rows, jq=bid>>8 -> 64 j.
// 256 thr. 16 half-chunks of 32 d; 3 rotating 8KB LDS buffers; 2-deep
// pipeline: stage c+2 while computing c; PIPE_SYNC(2) -> never drain to 0.
// LDS 32KB total -> 5 blocks/CU (20 waves/CU).
// Swizzled k layout: slot(j, gl) holds k[jbase+j][c*32 + (gl^(j&7))*4 ..+3]
//   stage: thread t, load m: row=(t>>3)+32m, src d-group=(t&7)^((t>>3)&7)
//   read:  lane j, group gr (wave-uniform): local group gl = gr^(j&7)
//   -> 64 lanes cover all 8 bank-groups: conflict-free ds_read_b128.
// Wave w owns contiguous d-groups {2w,2w+1} -> q s_loads contiguous (8
// floats/row/chunk), mergeable (R14 lesson: strided d-splits kill SMEM).
__global__ __launch_bounds__(256)
void manh_scores4(const float* __restrict__ q,
                  const float* __restrict__ k,
                  float* __restrict__ S)
{
    __shared__ __align__(16) float s_k[3][2048];   // 24 KB: 32-d chunk x3
    __shared__ __align__(16) float s_red[2048];    // 8 KB: 4 waves x 8 rows x 64 j

    const int t     = threadIdx.x;
    const int b     = blockIdx.x & 7;          // batch -> XCD locality
    const int itile = (blockIdx.x >> 3) & 31;
    const int jq    = blockIdx.x >> 8;         // 0..3
    const int ibase = itile * 8;
    const int jbase = jq * 64;

    const float* __restrict__ kb = k + (size_t)b * N_ * D_;

    // --- staging sources (pre-swizzled global, linear LDS dest) ---
    const int dgsw = (t & 7) ^ ((t >> 3) & 7);
    const float* ksrc0 = kb + (size_t)(jbase + (t >> 3)) * D_ + dgsw * 4;
    const float* ksrc1 = ksrc0 + (size_t)32 * D_;

#define STAGEA(cc, sb)                                          \
    {                                                           \
        load_lds_16B(ksrc0 + (cc) * 32, &s_k[sb][4 * t]);       \
        load_lds_16B(ksrc1 + (cc) * 32, &s_k[sb][4 * t + 1024]);\
    }

    // ---- prologue: 2-deep ----
    STAGEA(0, 0)
    STAGEA(1, 1)
    PIPE_SYNC(2);                      // chunk 0 resident everywhere

    const int w    = t >> 6;           // wave -> d-groups {2w, 2w+1}
    const int j    = t & 63;
    const int swz  = j & 7;
    const float* __restrict__ qrow = q + ((size_t)(b * N_ + ibase)) * D_;

    float a0 = 0.f, a1 = 0.f, a2 = 0.f, a3 = 0.f;
    float a4 = 0.f, a5 = 0.f, a6 = 0.f, a7 = 0.f;

    int buf = 0, sb = 2;
    for (int c = 0; c < 16; ++c) {
        if (c < 14) STAGEA(c + 2, sb)

        {
            const float* kcb = &s_k[buf][j << 5];
            #pragma unroll
            for (int g2 = 0; g2 < 2; ++g2) {
                const int gr = 2 * w + g2;                 // wave-uniform
                const float4 k4 = *(const float4*)(kcb + (((gr ^ swz) & 7) << 2));
                const int doff = c * 32 + gr * 4;
#define ACCR(A, R)                                                             \
                {                                                              \
                    const float4 q4 = *(const float4*)(qrow + (size_t)(R) * D_ + doff); \
                    A += (fabsf(q4.x - k4.x) + fabsf(q4.y - k4.y)) +           \
                         (fabsf(q4.z - k4.z) + fabsf(q4.w - k4.w));            \
                }
                ACCR(a0, 0) ACCR(a1, 1) ACCR(a2, 2) ACCR(a3, 3)
                ACCR(a4, 4) ACCR(a5, 5) ACCR(a6, 6) ACCR(a7, 7)
#undef ACCR
            }
        }

        if (c < 14)       PIPE_SYNC(2);    // chunk c+1 resident, c+2 in flight
        else if (c == 14) PIPE_SYNC(0);    // last chunk: single full drain
        buf = (buf == 2) ? 0 : buf + 1;
        sb  = (sb == 2) ? 0 : sb + 1;
    }
#undef STAGEA

    // ---- dump 8 row-partials, reduce 4 wave-quarters ----
    s_red[w * 512 + 0 * 64 + j] = a0;
    s_red[w * 512 + 1 * 64 + j] = a1;
    s_red[w * 512 + 2 * 64 + j] = a2;
    s_red[w * 512 + 3 * 64 + j] = a3;
    s_red[w * 512 + 4 * 64 + j] = a4;
    s_red[w * 512 + 5 * 64 + j] = a5;
    s_red[w * 512 + 6 * 64 + j] = a6;
    s_red[w * 512 + 7 * 64 + j] = a7;
    __syncthreads();

    #pragma unroll
    for (int e = t; e < 512; e += 256) {
        const int r  = e >> 6;                 // 0..7
        const int jj = e & 63;
        const int sl = r * 64 + jj;
        const float sum = (s_red[0 * 512 + sl] + s_red[1 * 512 + sl]) +
                          (s_red[2 * 512 + sl] + s_red[3 * 512 + sl]);
        S[(size_t)b * N_ * N_ + (size_t)(ibase + r) * N_ + jbase + jj] = -sum;
    }
}

// ================= Kernel B: softmax(S) @ v, 8 rows/block (verified R13) ===
__global__ __launch_bounds__(512, 4)
void manh_sm_pv8(const float* __restrict__ S,
                 const float* __restrict__ v,
                 float* __restrict__ out)
{
    __shared__ __align__(16) float s_w[8 * N_];      // 8 KB
    __shared__ __align__(16) float s_part[8 * 1024]; // 32 KB

    const int t     = threadIdx.x;
    const int lane  = t & 63;
    const int w     = t >> 6;              // 0..7
    const int b     = blockIdx.x & 7;
    const int itile = (blockIdx.x >> 3) & 31;
    const int dh    = blockIdx.x >> 8;     // 0..1
    const int i0    = itile * 8;

    *(float4*)&s_w[4 * t] =
        *(const float4*)(S + (size_t)b * N_ * N_ + (size_t)i0 * N_ + 4 * t);
    __syncthreads();

    {
        float* row = &s_w[w * N_];
        float v0 = row[lane];
        float v1 = row[lane + 64];
        float v2 = row[lane + 128];
        float v3 = row[lane + 192];
        float m = fmaxf(fmaxf(v0, v1), fmaxf(v2, v3));
        #pragma unroll
        for (int off = 32; off; off >>= 1) m = fmaxf(m, __shfl_xor(m, off));
        const float cc = 1.4426950408889634f;
        float e0 = exp2f((v0 - m) * cc);
        float e1 = exp2f((v1 - m) * cc);
        float e2 = exp2f((v2 - m) * cc);
        float e3 = exp2f((v3 - m) * cc);
        float s = (e0 + e1) + (e2 + e3);
        #pragma unroll
        for (int off = 32; off; off >>= 1) s += __shfl_xor(s, off);
        const float r = 1.0f / s;
        row[lane]       = e0 * r;
        row[lane + 64]  = e1 * r;
        row[lane + 128] = e2 * r;
        row[lane + 192] = e3 * r;
    }
    __syncthreads();

    const int dq    = t & 63;
    const int jh    = t >> 6;              // == wave -> s_w reads wave-uniform
    const int dbase = dh * 256 + dq * 4;
    const float* __restrict__ vb = v + (size_t)b * N_ * D_ + dbase;

    float4 a0 = make_float4(0.f,0.f,0.f,0.f), a1 = a0, a2 = a0, a3 = a0;
    float4 a4 = a0, a5 = a0, a6 = a0, a7 = a0;

#define PVROW(A, W)                                                            \
    A.x += (W).x * vv0.x + (W).y * vv1.x + (W).z * vv2.x + (W).w * vv3.x;      \
    A.y += (W).x * vv0.y + (W).y * vv1.y + (W).z * vv2.y + (W).w * vv3.y;      \
    A.z += (W).x * vv0.z + (W).y * vv1.z + (W).z * vv2.z + (W).w * vv3.z;      \
    A.w += (W).x * vv0.w + (W).y * vv1.w + (W).z * vv2.w + (W).w * vv3.w;

    #pragma unroll 2
    for (int jo = 0; jo < 32; jo += 4) {
        const int jj = jh * 32 + jo;
        const float4 vv0 = *(const float4*)(vb + (size_t)(jj + 0) * D_);
        const float4 vv1 = *(const float4*)(vb + (size_t)(jj + 1) * D_);
        const float4 vv2 = *(const float4*)(vb + (size_t)(jj + 2) * D_);
        const float4 vv3 = *(const float4*)(vb + (size_t)(jj + 3) * D_);
        const float4 w0 = *(const float4*)&s_w[0 * N_ + jj];
        const float4 w1 = *(const float4*)&s_w[1 * N_ + jj];
        const float4 w2 = *(const float4*)&s_w[2 * N_ + jj];
        const float4 w3 = *(const float4*)&s_w[3 * N_ + jj];
        const float4 w4 = *(const float4*)&s_w[4 * N_ + jj];
        const float4 w5 = *(const float4*)&s_w[5 * N_ + jj];
        const float4 w6 = *(const float4*)&s_w[6 * N_ + jj];
        const float4 w7 = *(const float4*)&s_w[7 * N_ + jj];
        PVROW(a0, w0) PVROW(a1, w1) PVROW(a2, w2) PVROW(a3, w3)
        PVROW(a4, w4) PVROW(a5, w5) PVROW(a6, w6) PVROW(a7, w7)
    }
#undef PVROW

    *(float4*)&s_part[jh * 1024 + 0 * 256 + dq * 4] = a0;
    *(float4*)&s_part[jh * 1024 + 1 * 256 + dq * 4] = a1;
    *(float4*)&s_part[jh * 1024 + 2 * 256 + dq * 4] = a2;
    *(float4*)&s_part[jh * 1024 + 3 * 256 + dq * 4] = a3;
    __syncthreads();
    if (t < 256) {
        const int r  = t >> 6;
        const int d4 = (t & 63) * 4;
        float4 s = make_float4(0.f,0.f,0.f,0.f);
        #pragma unroll
        for (int g = 0; g < 8; ++g) {
            const float4 p = *(const float4*)&s_part[g * 1024 + r * 256 + d4];
            s.x += p.x; s.y += p.y; s.z += p.z; s.w += p.w;
        }
        *(float4*)(out + ((size_t)(b * N_ + i0 + r)) * D_ + dh * 256 + d4) = s;
    }
    __syncthreads();
    *(float4*)&s_part[jh * 1024 + 0 * 256 + dq * 4] = a4;
    *(float4*)&s_part[jh * 1024 + 1 * 256 + dq * 4] = a5;
    *(float4*)&s_part[jh * 1024 + 2 * 256 + dq * 4] = a6;
    *(float4*)&s_part[jh * 1024 + 3 * 256 + dq * 4] = a7;
    __syncthreads();
    if (t < 256) {
        const int r  = t >> 6;
        const int d4 = (t & 63) * 4;
        float4 s = make_float4(0.f,0.f,0.f,0.f);
        #pragma unroll
        for (int g = 0; g < 8; ++g) {
            const float4 p = *(const float4*)&s_part[g * 1024 + r * 256 + d4];
            s.x += p.x; s.y += p.y; s.z += p.z; s.w += p.w;
        }
        *(float4*)(out + ((size_t)(b * N_ + i0 + 4 + r)) * D_ + dh * 256 + d4) = s;
    }
}

// ---------- Fallback (round-1 kernel) if ws can't hold S (2 MB) ----------
__global__ __launch_bounds__(256, 2)
void manh_attn_legacy(const float* __restrict__ q,
                      const float* __restrict__ k,
                      const float* __restrict__ v,
                      float* __restrict__ out)
{
    __shared__ float s_mat[4][N_];
    const int t   = threadIdx.x;
    const int bid = blockIdx.x;
    const int b   = bid >> 6;
    const int i0  = (bid & 63) * 4;

    const float* __restrict__ krow  = k + ((size_t)(b * N_ + t)) * D_;
    const float* __restrict__ qbase = q + ((size_t)(b * N_ + i0)) * D_;

    float acc0 = 0.f, acc1 = 0.f, acc2 = 0.f, acc3 = 0.f;
    #pragma unroll 4
    for (int d = 0; d < D_; d += 4) {
        const float4 kv = *(const float4*)(krow + d);
        const float4 q0 = *(const float4*)(qbase + d);
        const float4 q1 = *(const float4*)(qbase + D_ + d);
        const float4 q2 = *(const float4*)(qbase + 2 * D_ + d);
        const float4 q3 = *(const float4*)(qbase + 3 * D_ + d);
        acc0 += (fabsf(q0.x - kv.x) + fabsf(q0.y - kv.y)) + (fabsf(q0.z - kv.z) + fabsf(q0.w - kv.w));
        acc1 += (fabsf(q1.x - kv.x) + fabsf(q1.y - kv.y)) + (fabsf(q1.z - kv.z) + fabsf(q1.w - kv.w));
        acc2 += (fabsf(q2.x - kv.x) + fabsf(q2.y - kv.y)) + (fabsf(q2.z - kv.z) + fabsf(q2.w - kv.w));
        acc3 += (fabsf(q3.x - kv.x) + fabsf(q3.y - kv.y)) + (fabsf(q3.z - kv.z) + fabsf(q3.w - kv.w));
    }
    s_mat[0][t] = -acc0; s_mat[1][t] = -acc1; s_mat[2][t] = -acc2; s_mat[3][t] = -acc3;
    __syncthreads();
    {
        const int w = t >> 6;
        const int l = t & 63;
        float v0 = s_mat[w][l], v1 = s_mat[w][l + 64], v2 = s_mat[w][l + 128], v3 = s_mat[w][l + 192];
        float m = fmaxf(fmaxf(v0, v1), fmaxf(v2, v3));
        #pragma unroll
        for (int off = 32; off; off >>= 1) m = fmaxf(m, __shfl_xor(m, off));
        const float c = 1.4426950408889634f;
        float e0 = exp2f((v0 - m) * c), e1 = exp2f((v1 - m) * c);
        float e2 = exp2f((v2 - m) * c), e3 = exp2f((v3 - m) * c);
        float s = (e0 + e1) + (e2 + e3);
        #pragma unroll
        for (int off = 32; off; off >>= 1) s += __shfl_xor(s, off);
        const float r = 1.0f / s;
        s_mat[w][l] = e0 * r; s_mat[w][l + 64] = e1 * r;
        s_mat[w][l + 128] = e2 * r; s_mat[w][l + 192] = e3 * r;
    }
    __syncthreads();
    const int ig = t >> 7;
    const int d0 = (t & 127) * 4;
    const float* __restrict__ vbase = v + ((size_t)b * N_) * D_ + d0;
    const float* __restrict__ wr0 = &s_mat[2 * ig][0];
    const float* __restrict__ wr1 = &s_mat[2 * ig + 1][0];
    float4 a0 = make_float4(0.f, 0.f, 0.f, 0.f);
    float4 a1 = make_float4(0.f, 0.f, 0.f, 0.f);
#define PV_STEP(W0, W1, VV)                                     \
    a0.x += (W0) * (VV).x; a0.y += (W0) * (VV).y;               \
    a0.z += (W0) * (VV).z; a0.w += (W0) * (VV).w;               \
    a1.x += (W1) * (VV).x; a1.y += (W1) * (VV).y;               \
    a1.z += (W1) * (VV).z; a1.w += (W1) * (VV).w;
    #pragma unroll 2
    for (int j = 0; j < N_; j += 4) {
        const float4 w0 = *(const float4*)(wr0 + j);
        const float4 w1 = *(const float4*)(wr1 + j);
        const float4 vv0 = *(const float4*)(vbase + (size_t)(j + 0) * D_);
        const float4 vv1 = *(const float4*)(vbase + (size_t)(j + 1) * D_);
        const float4 vv2 = *(const float4*)(vbase + (size_t)(j + 2) * D_);
        const float4 vv3 = *(const float4*)(vbase + (size_t)(j + 3) * D_);
        PV_STEP(w0.x, w1.x, vv0)
        PV_STEP(w0.y, w1.y, vv1)
        PV_STEP(w0.z, w1.z, vv2)
        PV_STEP(w0.w, w1.w, vv3)
    }
#undef PV_STEP
    float* op = out + ((size_t)(b * N_ + i0 + 2 * ig)) * D_ + d0;
    *(float4*)op        = a0;
    *(float4*)(op + D_) = a1;
}

extern "C" void kernel_launch(void* const* d_in, const int* in_sizes, int n_in,
                              void* d_out, int out_size, void* d_ws, size_t ws_size,
                              hipStream_t stream)
{
    const float* q = (const float*)d_in[0];
    const float* k = (const float*)d_in[1];
    const float* v = (const float*)d_in[2];
    float* out = (float*)d_out;

    const size_t S_bytes = (size_t)B_ * N_ * N_ * sizeof(float);
    if (ws_size >= S_bytes) {
        float* S = (float*)d_ws;
        manh_scores4<<<dim3(1024), dim3(256), 0, stream>>>(q, k, S);
        manh_sm_pv8 <<<dim3(512), dim3(512), 0, stream>>>(S, v, out);
    } else {
        manh_attn_legacy<<<dim3(B_ * 64), dim3(256), 0, stream>>>(q, k, v, out);
    }
}

// Round 17
// 41.005 us; speedup vs baseline: 1.2816x; 1.2816x over previous
//
#include <hip/hip_runtime.h>

#define B_ 8
#define N_ 256
#define D_ 512

// async 16B global -> LDS. FULL-WAVE ONLY (exec-masked LDS-DMA corrupts LDS).
__device__ __forceinline__ void load_lds_16B(const float* g, float* l)
{
    __builtin_amdgcn_global_load_lds(
        (const __attribute__((address_space(1))) void*)g,
        (__attribute__((address_space(3))) void*)l, 16, 0, 0);
}

// ================= Kernel A: scores S[b][i][j] = -sum_d |q-k| =============
// grid 1024: b=bid&7, itile=(bid>>3)&31 -> 8 rows, jq=bid>>8 -> 64 j.
// 256 thr. Wave w = contiguous d-quarter [w*16, w*16+16) of each 64-d chunk,
// ALL 8 rows per thread (R15-verified mapping; k swizzle R12-verified).
// NEW vs R15: q comes from LDS (staged per 128-d chunk-pair via one 4KB
// full-wave DMA), read as wave-uniform ds_read_b128 broadcasts. NO SMEM in
// the loop -> no out-of-order s_load forcing lgkmcnt(0) drains of ds_reads,
// no sK$ thrash (4 blocks x 16KB q > 16KB scalar cache).
__global__ __launch_bounds__(256)
void manh_scores5(const float* __restrict__ q,
                  const float* __restrict__ k,
                  float* __restrict__ S)
{
    __shared__ __align__(16) float s_k[2][4096];   // 32 KB: 64-d k chunk dbuf
    __shared__ __align__(16) float s_q[2][1024];   // 8 KB: 128-d q pair dbuf
    float* s_red = &s_k[0][0];                     // 8 KB alias after loop

    const int t     = threadIdx.x;
    const int b     = blockIdx.x & 7;          // batch -> XCD locality
    const int itile = (blockIdx.x >> 3) & 31;
    const int jq    = blockIdx.x >> 8;         // 0..3
    const int ibase = itile * 8;
    const int jbase = jq * 64;

    const float* __restrict__ kb = k + (size_t)b * N_ * D_;
    const float* __restrict__ qb = q + ((size_t)(b * N_ + ibase)) * D_;

    // --- staging sources (pre-swizzled k global, linear LDS dest) ---
    const int dg = (t & 3) ^ ((t >> 3) & 3);
    const float* ksrc = kb + (size_t)(jbase + (t >> 2)) * D_ + dg * 4;
    // q pair p: thread t -> row t>>5, d-local (t&31)*4 within [p*128,(p+1)*128)
    const float* qsrc = qb + (size_t)(t >> 5) * D_ + (t & 31) * 4;

#define STAGEK(cc, sb)                                              \
    {                                                               \
        load_lds_16B(ksrc + (cc) * 64,      &s_k[sb][4 * t]);       \
        load_lds_16B(ksrc + (cc) * 64 + 16, &s_k[sb][1024 + 4 * t]);\
        load_lds_16B(ksrc + (cc) * 64 + 32, &s_k[sb][2048 + 4 * t]);\
        load_lds_16B(ksrc + (cc) * 64 + 48, &s_k[sb][3072 + 4 * t]);\
    }
#define STAGEQ(p)                                                   \
    load_lds_16B(qsrc + (p) * 128, &s_q[(p) & 1][4 * t]);

    // ---- prologue ----
    STAGEK(0, 0)
    STAGEQ(0)
    __syncthreads();                   // chunk 0 k + pair 0 q resident

    const int w    = t >> 6;           // wave = d-quarter
    const int j    = t & 63;
    const int swz  = (j >> 1) & 3;
    const int dlo  = __builtin_amdgcn_readfirstlane(w * 16);

    float a0 = 0.f, a1 = 0.f, a2 = 0.f, a3 = 0.f;
    float a4 = 0.f, a5 = 0.f, a6 = 0.f, a7 = 0.f;

    int kbuf = 0;
    for (int c = 0; c < 8; ++c) {
        if (c < 7) STAGEK(c + 1, kbuf ^ 1)
        if ((c & 1) == 0 && c < 6) STAGEQ((c >> 1) + 1)

        const float* kcb = &s_k[kbuf][w * 1024 + (j << 4)];
        // wave-uniform q base: pair (c>>1), half (c&1), quarter w
        const float* qc = &s_q[(c >> 1) & 1][(c & 1) * 64 + dlo];
        #pragma unroll
        for (int i = 0; i < 4; ++i) {
            const float4 k4 = *(const float4*)(kcb + ((i ^ swz) << 2));
#define ACCR(A, R)                                                             \
            {                                                                  \
                const float4 q4 = *(const float4*)(qc + (R) * 128 + i * 4);    \
                A += (fabsf(q4.x - k4.x) + fabsf(q4.y - k4.y)) +               \
                     (fabsf(q4.z - k4.z) + fabsf(q4.w - k4.w));                \
            }
            ACCR(a0, 0) ACCR(a1, 1) ACCR(a2, 2) ACCR(a3, 3)
            ACCR(a4, 4) ACCR(a5, 5) ACCR(a6, 6) ACCR(a7, 7)
#undef ACCR
        }

        __syncthreads();               // drains next-chunk DMA (issued early)
        kbuf ^= 1;
    }
#undef STAGEK
#undef STAGEQ

    // ---- dump 8 row-partials (s_red aliases s_k; last reads barriered) ----
    s_red[w * 512 + 0 * 64 + j] = a0;
    s_red[w * 512 + 1 * 64 + j] = a1;
    s_red[w * 512 + 2 * 64 + j] = a2;
    s_red[w * 512 + 3 * 64 + j] = a3;
    s_red[w * 512 + 4 * 64 + j] = a4;
    s_red[w * 512 + 5 * 64 + j] = a5;
    s_red[w * 512 + 6 * 64 + j] = a6;
    s_red[w * 512 + 7 * 64 + j] = a7;
    __syncthreads();

    #pragma unroll
    for (int e = t; e < 512; e += 256) {
        const int r  = e >> 6;                 // 0..7
        const int jj = e & 63;
        const int sl = r * 64 + jj;
        const float sum = (s_red[0 * 512 + sl] + s_red[1 * 512 + sl]) +
                          (s_red[2 * 512 + sl] + s_red[3 * 512 + sl]);
        S[(size_t)b * N_ * N_ + (size_t)(ibase + r) * N_ + jbase + jj] = -sum;
    }
}

// ================= Kernel B: softmax(S) @ v, 8 rows/block (verified R13) ===
__global__ __launch_bounds__(512, 4)
void manh_sm_pv8(const float* __restrict__ S,
                 const float* __restrict__ v,
                 float* __restrict__ out)
{
    __shared__ __align__(16) float s_w[8 * N_];      // 8 KB
    __shared__ __align__(16) float s_part[8 * 1024]; // 32 KB

    const int t     = threadIdx.x;
    const int lane  = t & 63;
    const int w     = t >> 6;              // 0..7
    const int b     = blockIdx.x & 7;
    const int itile = (blockIdx.x >> 3) & 31;
    const int dh    = blockIdx.x >> 8;     // 0..1
    const int i0    = itile * 8;

    *(float4*)&s_w[4 * t] =
        *(const float4*)(S + (size_t)b * N_ * N_ + (size_t)i0 * N_ + 4 * t);
    __syncthreads();

    {
        float* row = &s_w[w * N_];
        float v0 = row[lane];
        float v1 = row[lane + 64];
        float v2 = row[lane + 128];
        float v3 = row[lane + 192];
        float m = fmaxf(fmaxf(v0, v1), fmaxf(v2, v3));
        #pragma unroll
        for (int off = 32; off; off >>= 1) m = fmaxf(m, __shfl_xor(m, off));
        const float cc = 1.4426950408889634f;
        float e0 = exp2f((v0 - m) * cc);
        float e1 = exp2f((v1 - m) * cc);
        float e2 = exp2f((v2 - m) * cc);
        float e3 = exp2f((v3 - m) * cc);
        float s = (e0 + e1) + (e2 + e3);
        #pragma unroll
        for (int off = 32; off; off >>= 1) s += __shfl_xor(s, off);
        const float r = 1.0f / s;
        row[lane]       = e0 * r;
        row[lane + 64]  = e1 * r;
        row[lane + 128] = e2 * r;
        row[lane + 192] = e3 * r;
    }
    __syncthreads();

    const int dq    = t & 63;
    const int jh    = t >> 6;              // == wave -> s_w reads wave-uniform
    const int dbase = dh * 256 + dq * 4;
    const float* __restrict__ vb = v + (size_t)b * N_ * D_ + dbase;

    float4 a0 = make_float4(0.f,0.f,0.f,0.f), a1 = a0, a2 = a0, a3 = a0;
    float4 a4 = a0, a5 = a0, a6 = a0, a7 = a0;

#define PVROW(A, W)                                                            \
    A.x += (W).x * vv0.x + (W).y * vv1.x + (W).z * vv2.x + (W).w * vv3.x;      \
    A.y += (W).x * vv0.y + (W).y * vv1.y + (W).z * vv2.y + (W).w * vv3.y;      \
    A.z += (W).x * vv0.z + (W).y * vv1.z + (W).z * vv2.z + (W).w * vv3.z;      \
    A.w += (W).x * vv0.w + (W).y * vv1.w + (W).z * vv2.w + (W).w * vv3.w;

    #pragma unroll 2
    for (int jo = 0; jo < 32; jo += 4) {
        const int jj = jh * 32 + jo;
        const float4 vv0 = *(const float4*)(vb + (size_t)(jj + 0) * D_);
        const float4 vv1 = *(const float4*)(vb + (size_t)(jj + 1) * D_);
        const float4 vv2 = *(const float4*)(vb + (size_t)(jj + 2) * D_);
        const float4 vv3 = *(const float4*)(vb + (size_t)(jj + 3) * D_);
        const float4 w0 = *(const float4*)&s_w[0 * N_ + jj];
        const float4 w1 = *(const float4*)&s_w[1 * N_ + jj];
        const float4 w2 = *(const float4*)&s_w[2 * N_ + jj];
        const float4 w3 = *(const float4*)&s_w[3 * N_ + jj];
        const float4 w4 = *(const float4*)&s_w[4 * N_ + jj];
        const float4 w5 = *(const float4*)&s_w[5 * N_ + jj];
        const float4 w6 = *(const float4*)&s_w[6 * N_ + jj];
        const float4 w7 = *(const float4*)&s_w[7 * N_ + jj];
        PVROW(a0, w0) PVROW(a1, w1) PVROW(a2, w2) PVROW(a3, w3)
        PVROW(a4, w4) PVROW(a5, w5) PVROW(a6, w6) PVROW(a7, w7)
    }
#undef PVROW

    *(float4*)&s_part[jh * 1024 + 0 * 256 + dq * 4] = a0;
    *(float4*)&s_part[jh * 1024 + 1 * 256 + dq * 4] = a1;
    *(float4*)&s_part[jh * 1024 + 2 * 256 + dq * 4] = a2;
    *(float4*)&s_part[jh * 1024 + 3 * 256 + dq * 4] = a3;
    __syncthreads();
    if (t < 256) {
        const int r  = t >> 6;
        const int d4 = (t & 63) * 4;
        float4 s = make_float4(0.f,0.f,0.f,0.f);
        #pragma unroll
        for (int g = 0; g < 8; ++g) {
            const float4 p = *(const float4*)&s_part[g * 1024 + r * 256 + d4];
            s.x += p.x; s.y += p.y; s.z += p.z; s.w += p.w;
        }
        *(float4*)(out + ((size_t)(b * N_ + i0 + r)) * D_ + dh * 256 + d4) = s;
    }
    __syncthreads();
    *(float4*)&s_part[jh * 1024 + 0 * 256 + dq * 4] = a4;
    *(float4*)&s_part[jh * 1024 + 1 * 256 + dq * 4] = a5;
    *(float4*)&s_part[jh * 1024 + 2 * 256 + dq * 4] = a6;
    *(float4*)&s_part[jh * 1024 + 3 * 256 + dq * 4] = a7;
    __syncthreads();
    if (t < 256) {
        const int r  = t >> 6;
        const int d4 = (t & 63) * 4;
        float4 s = make_float4(0.f,0.f,0.f,0.f);
        #pragma unroll
        for (int g = 0; g < 8; ++g) {
            const float4 p = *(const float4*)&s_part[g * 1024 + r * 256 + d4];
            s.x += p.x; s.y += p.y; s.z += p.z; s.w += p.w;
        }
        *(float4*)(out + ((size_t)(b * N_ + i0 + 4 + r)) * D_ + dh * 256 + d4) = s;
    }
}

// ---------- Fallback (round-1 kernel) if ws can't hold S (2 MB) ----------
__global__ __launch_bounds__(256, 2)
void manh_attn_legacy(const float* __restrict__ q,
                      const float* __restrict__ k,
                      const float* __restrict__ v,
                      float* __restrict__ out)
{
    __shared__ float s_mat[4][N_];
    const int t   = threadIdx.x;
    const int bid = blockIdx.x;
    const int b   = bid >> 6;
    const int i0  = (bid & 63) * 4;

    const float* __restrict__ krow  = k + ((size_t)(b * N_ + t)) * D_;
    const float* __restrict__ qbase = q + ((size_t)(b * N_ + i0)) * D_;

    float acc0 = 0.f, acc1 = 0.f, acc2 = 0.f, acc3 = 0.f;
    #pragma unroll 4
    for (int d = 0; d < D_; d += 4) {
        const float4 kv = *(const float4*)(krow + d);
        const float4 q0 = *(const float4*)(qbase + d);
        const float4 q1 = *(const float4*)(qbase + D_ + d);
        const float4 q2 = *(const float4*)(qbase + 2 * D_ + d);
        const float4 q3 = *(const float4*)(qbase + 3 * D_ + d);
        acc0 += (fabsf(q0.x - kv.x) + fabsf(q0.y - kv.y)) + (fabsf(q0.z - kv.z) + fabsf(q0.w - kv.w));
        acc1 += (fabsf(q1.x - kv.x) + fabsf(q1.y - kv.y)) + (fabsf(q1.z - kv.z) + fabsf(q1.w - kv.w));
        acc2 += (fabsf(q2.x - kv.x) + fabsf(q2.y - kv.y)) + (fabsf(q2.z - kv.z) + fabsf(q2.w - kv.w));
        acc3 += (fabsf(q3.x - kv.x) + fabsf(q3.y - kv.y)) + (fabsf(q3.z - kv.z) + fabsf(q3.w - kv.w));
    }
    s_mat[0][t] = -acc0; s_mat[1][t] = -acc1; s_mat[2][t] = -acc2; s_mat[3][t] = -acc3;
    __syncthreads();
    {
        const int w = t >> 6;
        const int l = t & 63;
        float v0 = s_mat[w][l], v1 = s_mat[w][l + 64], v2 = s_mat[w][l + 128], v3 = s_mat[w][l + 192];
        float m = fmaxf(fmaxf(v0, v1), fmaxf(v2, v3));
        #pragma unroll
        for (int off = 32; off; off >>= 1) m = fmaxf(m, __shfl_xor(m, off));
        const float c = 1.4426950408889634f;
        float e0 = exp2f((v0 - m) * c), e1 = exp2f((v1 - m) * c);
        float e2 = exp2f((v2 - m) * c), e3 = exp2f((v3 - m) * c);
        float s = (e0 + e1) + (e2 + e3);
        #pragma unroll
        for (int off = 32; off; off >>= 1) s += __shfl_xor(s, off);
        const float r = 1.0f / s;
        s_mat[w][l] = e0 * r; s_mat[w][l + 64] = e1 * r;
        s_mat[w][l + 128] = e2 * r; s_mat[w][l + 192] = e3 * r;
    }
    __syncthreads();
    const int ig = t >> 7;
    const int d0 = (t & 127) * 4;
    const float* __restrict__ vbase = v + ((size_t)b * N_) * D_ + d0;
    const float* __restrict__ wr0 = &s_mat[2 * ig][0];
    const float* __restrict__ wr1 = &s_mat[2 * ig + 1][0];
    float4 a0 = make_float4(0.f, 0.f, 0.f, 0.f);
    float4 a1 = make_float4(0.f, 0.f, 0.f, 0.f);
#define PV_STEP(W0, W1, VV)                                     \
    a0.x += (W0) * (VV).x; a0.y += (W0) * (VV).y;               \
    a0.z += (W0) * (VV).z; a0.w += (W0) * (VV).w;               \
    a1.x += (W1) * (VV).x; a1.y += (W1) * (VV).y;               \
    a1.z += (W1) * (VV).z; a1.w += (W1) * (VV).w;
    #pragma unroll 2
    for (int j = 0; j < N_; j += 4) {
        const float4 w0 = *(const float4*)(wr0 + j);
        const float4 w1 = *(const float4*)(wr1 + j);
        const float4 vv0 = *(const float4*)(vbase + (size_t)(j + 0) * D_);
        const float4 vv1 = *(const float4*)(vbase + (size_t)(j + 1) * D_);
        const float4 vv2 = *(const float4*)(vbase + (size_t)(j + 2) * D_);
        const float4 vv3 = *(const float4*)(vbase + (size_t)(j + 3) * D_);
        PV_STEP(w0.x, w1.x, vv0)
        PV_STEP(w0.y, w1.y, vv1)
        PV_STEP(w0.z, w1.z, vv2)
        PV_STEP(w0.w, w1.w, vv3)
    }
#undef PV_STEP
    float* op = out + ((size_t)(b * N_ + i0 + 2 * ig)) * D_ + d0;
    *(float4*)op        = a0;
    *(float4*)(op + D_) = a1;
}

extern "C" void kernel_launch(void* const* d_in, const int* in_sizes, int n_in,
                              void* d_out, int out_size, void* d_ws, size_t ws_size,
                              hipStream_t stream)
{
    const float* q = (const float*)d_in[0];
    const float* k = (const float*)d_in[1];
    const float* v = (const float*)d_in[2];
    float* out = (float*)d_out;

    const size_t S_bytes = (size_t)B_ * N_ * N_ * sizeof(float);
    if (ws_size >= S_bytes) {
        float* S = (float*)d_ws;
        manh_scores5<<<dim3(1024), dim3(256), 0, stream>>>(q, k, S);
        manh_sm_pv8 <<<dim3(512), dim3(512), 0, stream>>>(S, v, out);
    } else {
        manh_attn_legacy<<<dim3(B_ * 64), dim3(256), 0, stream>>>(q, k, v, out);
    }
}